// Round 1
// baseline (1075.773 us; speedup 1.0000x reference)
//
#include <hip/hip_runtime.h>
#include <hip/hip_bf16.h>
#include <float.h>
#include <cstdint>

// ---------------------------------------------------------------------------
// RCSLS: out = ( topk10sum(X_trans@Z_tgt^T)/10 + topk10sum(Y_tgt@Z_trans^T)/10
//               - 2*sum(X_trans*Y_tgt) ) / 4096
// B=4096, N=32768, d=512, k=10.  Inputs f32; GEMMs done in bf16 MFMA.
// ---------------------------------------------------------------------------

#define B_ROWS 4096
#define N_COLS 32768
#define D_K    512
#define BM     128
#define BN     128
#define BKT    64
#define NCHUNK (N_COLS / BN)   // 256
#define KSEL   10

typedef __bf16 bf16x8 __attribute__((ext_vector_type(8)));
typedef float  f32x4  __attribute__((ext_vector_type(4)));

__device__ __forceinline__ unsigned short f2bf(float f) {
    unsigned int u = __float_as_uint(f);
    u += 0x7FFFu + ((u >> 16) & 1u);   // RNE
    return (unsigned short)(u >> 16);
}

__device__ __forceinline__ void gload_lds16(const void* g, void* l) {
    __builtin_amdgcn_global_load_lds(
        (const __attribute__((address_space(1))) unsigned int*)(uintptr_t)g,
        (__attribute__((address_space(3))) unsigned int*)(uintptr_t)l,
        16, 0, 0);
}

// ---- zero the 3 scalar accumulators -----------------------------------------
__global__ void zero_scalars(float* sc) {
    if (threadIdx.x < 3) sc[threadIdx.x] = 0.0f;
}

// ---- f32 -> bf16 conversion -------------------------------------------------
__global__ void cvt_kernel(const float4* __restrict__ src,
                           ushort4* __restrict__ dst, int n4) {
    int i = blockIdx.x * blockDim.x + threadIdx.x;
    int stride = gridDim.x * blockDim.x;
    for (; i < n4; i += stride) {
        float4 f = src[i];
        ushort4 u;
        u.x = f2bf(f.x); u.y = f2bf(f.y); u.z = f2bf(f.z); u.w = f2bf(f.w);
        dst[i] = u;
    }
}

// ---- 2*sum(x*y) term: accumulate sum(x*y) into sc[0] ------------------------
__global__ void dot_kernel(const float* __restrict__ x,
                           const float* __restrict__ y,
                           float* __restrict__ acc, int n) {
    int i = blockIdx.x * blockDim.x + threadIdx.x;
    int stride = gridDim.x * blockDim.x;
    float s = 0.0f;
    for (; i < n; i += stride) s += x[i] * y[i];
    for (int o = 32; o > 0; o >>= 1) s += __shfl_down(s, o);
    __shared__ float wsum[4];
    int lane = threadIdx.x & 63, w = threadIdx.x >> 6;
    if (lane == 0) wsum[w] = s;
    __syncthreads();
    if (threadIdx.x == 0)
        atomicAdd(acc, wsum[0] + wsum[1] + wsum[2] + wsum[3]);
}

// ---- bf16 GEMM (A[4096,512] @ Bm[32768,512]^T) + per-row per-chunk top-10 ---
// Grid: (NCHUNK, B_ROWS/BM). Block: 256 threads (4 waves, each 64x64).
__global__ __launch_bounds__(256, 2)
void gemm_topk_kernel(const unsigned short* __restrict__ A,
                      const unsigned short* __restrict__ Bm,
                      float* __restrict__ P) {
    __shared__ __align__(128) float smemf[BM * 129];  // 66048 B; staging aliases front
    unsigned short* Alds = (unsigned short*)smemf;    // [128][64] bf16, 16 KB
    unsigned short* Blds = Alds + BM * BKT;           // [128][64] bf16, 16 KB

    const int tid  = threadIdx.x;
    const int lane = tid & 63;
    const int w    = tid >> 6;
    const int wm   = w >> 1;          // wave row (0..1)
    const int wn   = w & 1;           // wave col (0..1)
    const int bn   = blockIdx.x;      // column chunk
    const int row0 = blockIdx.y * BM;
    const int col0 = bn * BN;
    const int quad = lane >> 4;
    const int mrow = lane & 15;

    f32x4 acc[4][4];
    #pragma unroll
    for (int mi = 0; mi < 4; ++mi)
        #pragma unroll
        for (int ni = 0; ni < 4; ++ni)
            acc[mi][ni] = (f32x4){0.f, 0.f, 0.f, 0.f};

    for (int kt = 0; kt < D_K; kt += BKT) {
        // stage A and B tiles: 16 wave-transfers each (1024 B per transfer)
        #pragma unroll
        for (int c = 0; c < 4; ++c) {
            int seg = w * 4 + c;                 // 0..15, 8 rows per seg
            int r   = seg * 8 + (lane >> 3);
            int kc  = (lane & 7) * 8;
            const unsigned short* ga = A  + (size_t)(row0 + r) * D_K + kt + kc;
            const unsigned short* gb = Bm + (size_t)(col0 + r) * D_K + kt + kc;
            gload_lds16(ga, Alds + seg * 512);   // wave-uniform LDS base
            gload_lds16(gb, Blds + seg * 512);
        }
        __syncthreads();
        #pragma unroll
        for (int kk = 0; kk < BKT; kk += 32) {
            bf16x8 af[4], bf[4];
            #pragma unroll
            for (int mi = 0; mi < 4; ++mi)
                af[mi] = *(const bf16x8*)(Alds + (wm * 64 + mi * 16 + mrow) * BKT + kk + quad * 8);
            #pragma unroll
            for (int ni = 0; ni < 4; ++ni)
                bf[ni] = *(const bf16x8*)(Blds + (wn * 64 + ni * 16 + mrow) * BKT + kk + quad * 8);
            #pragma unroll
            for (int mi = 0; mi < 4; ++mi)
                #pragma unroll
                for (int ni = 0; ni < 4; ++ni)
                    acc[mi][ni] = __builtin_amdgcn_mfma_f32_16x16x32_bf16(
                        af[mi], bf[ni], acc[mi][ni], 0, 0, 0);
        }
        __syncthreads();  // also protects LDS reuse by epilogue
    }

    // ---- dump C tile to LDS (stride 129 floats: conflict-light) ----
    float* Clds = smemf;
    #pragma unroll
    for (int mi = 0; mi < 4; ++mi) {
        int r = wm * 64 + mi * 16 + quad * 4;
        #pragma unroll
        for (int ni = 0; ni < 4; ++ni) {
            int cc = wn * 64 + ni * 16 + mrow;
            #pragma unroll
            for (int reg = 0; reg < 4; ++reg)
                Clds[(r + reg) * 129 + cc] = acc[mi][ni][reg];
        }
    }
    __syncthreads();

    // ---- per-half-row sorted top-10 (2 threads per row, 64 cols each) ----
    int rrow = tid & 127;
    int half = tid >> 7;
    const float* rp = Clds + rrow * 129 + half * 64;
    float t[KSEL];
    #pragma unroll
    for (int i = 0; i < KSEL; ++i) t[i] = -FLT_MAX;
    for (int j = 0; j < 64; ++j) {
        float v = rp[j];
        if (v > t[KSEL - 1]) {
            #pragma unroll
            for (int i = 0; i < KSEL; ++i) {
                float hi = fmaxf(t[i], v);
                v = fminf(t[i], v);
                t[i] = hi;
            }
        }
    }
    __syncthreads();
    float* lists = smemf;                 // 256 x 10 floats (reuse LDS)
    #pragma unroll
    for (int i = 0; i < KSEL; ++i) lists[tid * KSEL + i] = t[i];
    __syncthreads();

    // ---- merge the two sorted half-lists, write chunk top-10 to global ----
    if (tid < 128) {
        const float* pa = lists + tid * KSEL;
        const float* pb = lists + (tid + 128) * KSEL;
        float* Pg = P + ((size_t)(row0 + tid) * NCHUNK + bn) * KSEL;
        int ia = 0, ib = 0;
        #pragma unroll
        for (int i = 0; i < KSEL; ++i) {
            float av = pa[ia], bv = pb[ib];
            float mx = fmaxf(av, bv);
            if (av >= bv) ia++; else ib++;
            Pg[i] = mx;
        }
    }
}

// ---- per-row merge of 256 chunk top-10s -> exact row top-10, sum into acc ---
__global__ void merge_topk_kernel(const float* __restrict__ P,
                                  float* __restrict__ fk_acc) {
    const int NC = NCHUNK * KSEL;   // 2560
    __shared__ float vals[NCHUNK * KSEL];
    __shared__ float wred[4];
    __shared__ float Mv_s;
    __shared__ int claim;
    int row = blockIdx.x;
    for (int i = threadIdx.x; i < NC; i += 256)
        vals[i] = P[(size_t)row * NC + i];
    __syncthreads();
    float sum10 = 0.0f;
    int lane = threadIdx.x & 63, w = threadIdx.x >> 6;
    for (int it = 0; it < KSEL; ++it) {
        float m = -FLT_MAX;
        for (int i = threadIdx.x; i < NC; i += 256) m = fmaxf(m, vals[i]);
        for (int o = 32; o > 0; o >>= 1) m = fmaxf(m, __shfl_down(m, o));
        if (lane == 0) wred[w] = m;
        __syncthreads();
        if (threadIdx.x == 0) {
            Mv_s = fmaxf(fmaxf(wred[0], wred[1]), fmaxf(wred[2], wred[3]));
            claim = 0;
        }
        __syncthreads();
        float Mv = Mv_s;
        for (int i = threadIdx.x; i < NC; i += 256) {
            if (vals[i] == Mv) {
                if (atomicCAS(&claim, 0, 1) == 0) vals[i] = -FLT_MAX;
                break;
            }
        }
        sum10 += Mv;
        __syncthreads();
    }
    if (threadIdx.x == 0) atomicAdd(fk_acc, sum10);
}

// ---- final scalar -----------------------------------------------------------
__global__ void finalize_kernel(const float* __restrict__ sc,
                                float* __restrict__ out) {
    if (threadIdx.x == 0) {
        float f = (sc[1] * 0.1f + sc[2] * 0.1f - 2.0f * sc[0]) * (1.0f / 4096.0f);
        out[0] = f;
    }
}

extern "C" void kernel_launch(void* const* d_in, const int* in_sizes, int n_in,
                              void* d_out, int out_size, void* d_ws, size_t ws_size,
                              hipStream_t stream) {
    const float* X_trans = (const float*)d_in[1];
    const float* Y_tgt   = (const float*)d_in[2];
    const float* Z_trans = (const float*)d_in[4];
    const float* Z_tgt   = (const float*)d_in[5];

    char* ws = (char*)d_ws;
    float* sc = (float*)ws;                                  // [0]=dot [1]=fk0 [2]=fk1
    unsigned short* A0 = (unsigned short*)(ws + 256);        // X_trans bf16 [4096,512]
    unsigned short* A1 = A0 + (size_t)B_ROWS * D_K;          // Y_tgt  bf16
    unsigned short* B0 = A1 + (size_t)B_ROWS * D_K;          // Z_tgt  bf16 [32768,512]
    unsigned short* B1 = B0 + (size_t)N_COLS * D_K;          // Z_trans bf16
    float* P = (float*)(B1 + (size_t)N_COLS * D_K);          // partials [4096][256][10]

    zero_scalars<<<1, 64, 0, stream>>>(sc);

    cvt_kernel<<<2048, 256, 0, stream>>>((const float4*)X_trans, (ushort4*)A0,
                                         B_ROWS * D_K / 4);
    cvt_kernel<<<2048, 256, 0, stream>>>((const float4*)Y_tgt, (ushort4*)A1,
                                         B_ROWS * D_K / 4);
    cvt_kernel<<<16384, 256, 0, stream>>>((const float4*)Z_tgt, (ushort4*)B0,
                                          N_COLS * D_K / 4);
    cvt_kernel<<<16384, 256, 0, stream>>>((const float4*)Z_trans, (ushort4*)B1,
                                          N_COLS * D_K / 4);

    dot_kernel<<<1024, 256, 0, stream>>>(X_trans, Y_tgt, sc + 0, B_ROWS * D_K);

    dim3 ggrid(NCHUNK, B_ROWS / BM);
    gemm_topk_kernel<<<ggrid, 256, 0, stream>>>(A0, B0, P);
    merge_topk_kernel<<<B_ROWS, 256, 0, stream>>>(P, sc + 1);
    gemm_topk_kernel<<<ggrid, 256, 0, stream>>>(A1, B1, P);
    merge_topk_kernel<<<B_ROWS, 256, 0, stream>>>(P, sc + 2);

    finalize_kernel<<<1, 64, 0, stream>>>(sc, (float*)d_out);
}

// Round 2
// 889.899 us; speedup vs baseline: 1.2089x; 1.2089x over previous
//
#include <hip/hip_runtime.h>
#include <hip/hip_bf16.h>
#include <float.h>
#include <cstdint>

// ---------------------------------------------------------------------------
// RCSLS: out = ( topk10sum(X_trans@Z_tgt^T)/10 + topk10sum(Y_tgt@Z_trans^T)/10
//               - 2*sum(X_trans*Y_tgt) ) / 4096
// B=4096, N=32768, d=512, k=10.  Inputs f32; GEMMs done in bf16 MFMA.
// ---------------------------------------------------------------------------

#define B_ROWS 4096
#define N_COLS 32768
#define D_K    512
#define BM     128
#define BN     128
#define BKT    64
#define NCHUNK (N_COLS / BN)   // 256
#define KSEL   10
#define CSTRIDE 130            // bf16 C-dump stride (shorts)

typedef __bf16 bf16x8 __attribute__((ext_vector_type(8)));
typedef float  f32x4  __attribute__((ext_vector_type(4)));

__device__ __forceinline__ unsigned short f2bf(float f) {
    unsigned int u = __float_as_uint(f);
    u += 0x7FFFu + ((u >> 16) & 1u);   // RNE
    return (unsigned short)(u >> 16);
}

__device__ __forceinline__ void gload_lds16(const void* g, void* l) {
    __builtin_amdgcn_global_load_lds(
        (const __attribute__((address_space(1))) unsigned int*)(uintptr_t)g,
        (__attribute__((address_space(3))) unsigned int*)(uintptr_t)l,
        16, 0, 0);
}

// ---- zero the 3 scalar accumulators -----------------------------------------
__global__ void zero_scalars(float* sc) {
    if (threadIdx.x < 3) sc[threadIdx.x] = 0.0f;
}

// ---- f32 -> bf16 conversion -------------------------------------------------
__global__ void cvt_kernel(const float4* __restrict__ src,
                           ushort4* __restrict__ dst, int n4) {
    int i = blockIdx.x * blockDim.x + threadIdx.x;
    int stride = gridDim.x * blockDim.x;
    for (; i < n4; i += stride) {
        float4 f = src[i];
        ushort4 u;
        u.x = f2bf(f.x); u.y = f2bf(f.y); u.z = f2bf(f.z); u.w = f2bf(f.w);
        dst[i] = u;
    }
}

// ---- 2*sum(x*y) term: accumulate sum(x*y) into sc[0] ------------------------
__global__ void dot_kernel(const float* __restrict__ x,
                           const float* __restrict__ y,
                           float* __restrict__ acc, int n) {
    int i = blockIdx.x * blockDim.x + threadIdx.x;
    int stride = gridDim.x * blockDim.x;
    float s = 0.0f;
    for (; i < n; i += stride) s += x[i] * y[i];
    for (int o = 32; o > 0; o >>= 1) s += __shfl_down(s, o);
    __shared__ float wsum[4];
    int lane = threadIdx.x & 63, w = threadIdx.x >> 6;
    if (lane == 0) wsum[w] = s;
    __syncthreads();
    if (threadIdx.x == 0)
        atomicAdd(acc, wsum[0] + wsum[1] + wsum[2] + wsum[3]);
}

// ---- bf16 GEMM (A[4096,512] @ Bm[32768,512]^T) + per-row per-chunk top-10 ---
// Grid: (NCHUNK, B_ROWS/BM). Block: 256 threads (4 waves, each 64x64).
// LDS layout (33280 B total, aliased):
//   during GEMM : Alds bf16[16 segs][512]  (16 KB)  | Blds bf16[16][512] (16 KB)
//                 segment s (=rb*2+kk32): lane l holds row rb*16+(l&15),
//                 cols kk32*32+(l>>4)*8 .. +8  -> fragment read = base+lane*16
//   epilogue    : Cs bf16[128][130]
__global__ __launch_bounds__(256, 3)
void gemm_topk_kernel(const unsigned short* __restrict__ A,
                      const unsigned short* __restrict__ Bm,
                      float* __restrict__ P) {
    __shared__ __align__(128) unsigned short smem[BM * CSTRIDE]; // 33280 B
    unsigned short* Alds = smem;             // 16 segs * 512 shorts
    unsigned short* Blds = smem + 16 * 512;

    const int tid  = threadIdx.x;
    const int lane = tid & 63;
    const int w    = tid >> 6;
    const int wm   = w >> 1;          // wave row (0..1)
    const int wn   = w & 1;           // wave col (0..1)
    const int bn   = blockIdx.x;      // column chunk
    const int row0 = blockIdx.y * BM;
    const int col0 = bn * BN;
    const int quad = lane >> 4;
    const int mrow = lane & 15;

    // per-lane global staging offsets (segment s = w*4+c)
    //   row-in-tile = (s>>1)*16 + (lane&15); col = (s&1)*32 + (lane>>4)*8
    const unsigned short* gA[4];
    const unsigned short* gB[4];
    #pragma unroll
    for (int c = 0; c < 4; ++c) {
        int s   = w * 4 + c;
        int r   = (s >> 1) * 16 + mrow;
        int kc  = (s & 1) * 32 + quad * 8;
        gA[c] = A  + (size_t)(row0 + r) * D_K + kc;
        gB[c] = Bm + (size_t)(col0 + r) * D_K + kc;
    }

    f32x4 acc[4][4];
    #pragma unroll
    for (int mi = 0; mi < 4; ++mi)
        #pragma unroll
        for (int ni = 0; ni < 4; ++ni)
            acc[mi][ni] = (f32x4){0.f, 0.f, 0.f, 0.f};

    for (int kt = 0; kt < D_K; kt += BKT) {
        #pragma unroll
        for (int c = 0; c < 4; ++c) {
            int s = w * 4 + c;
            gload_lds16(gA[c] + kt, Alds + s * 512);
            gload_lds16(gB[c] + kt, Blds + s * 512);
        }
        __syncthreads();
        #pragma unroll
        for (int kk32 = 0; kk32 < 2; ++kk32) {
            bf16x8 af[4], bfr[4];
            #pragma unroll
            for (int mi = 0; mi < 4; ++mi)
                af[mi] = *(const bf16x8*)(Alds + ((wm * 4 + mi) * 2 + kk32) * 512 + lane * 8);
            #pragma unroll
            for (int ni = 0; ni < 4; ++ni)
                bfr[ni] = *(const bf16x8*)(Blds + ((wn * 4 + ni) * 2 + kk32) * 512 + lane * 8);
            #pragma unroll
            for (int mi = 0; mi < 4; ++mi)
                #pragma unroll
                for (int ni = 0; ni < 4; ++ni)
                    acc[mi][ni] = __builtin_amdgcn_mfma_f32_16x16x32_bf16(
                        af[mi], bfr[ni], acc[mi][ni], 0, 0, 0);
        }
        __syncthreads();
    }

    // ---- dump C tile to LDS as bf16, stride 130 shorts ----
    unsigned short* Cs = smem;
    #pragma unroll
    for (int mi = 0; mi < 4; ++mi) {
        int r = wm * 64 + mi * 16 + quad * 4;
        #pragma unroll
        for (int ni = 0; ni < 4; ++ni) {
            int cc = wn * 64 + ni * 16 + mrow;
            #pragma unroll
            for (int reg = 0; reg < 4; ++reg)
                Cs[(r + reg) * CSTRIDE + cc] = f2bf(acc[mi][ni][reg]);
        }
    }
    __syncthreads();

    // ---- per-half-row branchless top-10: row = w*32 + (lane>>1), half = lane&1
    int row  = w * 32 + (lane >> 1);
    int half = lane & 1;
    const unsigned int* rp =
        (const unsigned int*)(Cs + row * CSTRIDE + half * 64);
    float t[KSEL];
    #pragma unroll
    for (int i = 0; i < KSEL; ++i) t[i] = -FLT_MAX;
    #pragma unroll 8
    for (int j = 0; j < 32; ++j) {
        unsigned int pv = rp[j];
        float v0 = __uint_as_float(pv << 16);
        float v1 = __uint_as_float(pv & 0xffff0000u);
        #pragma unroll
        for (int i = 0; i < KSEL; ++i) {
            float hi = fmaxf(t[i], v0); v0 = fminf(t[i], v0); t[i] = hi;
        }
        #pragma unroll
        for (int i = 0; i < KSEL; ++i) {
            float hi = fmaxf(t[i], v1); v1 = fminf(t[i], v1); t[i] = hi;
        }
    }

    // ---- merge the two sorted half-lists via shfl_xor(1); write 5 each ----
    float pt[KSEL];
    #pragma unroll
    for (int i = 0; i < KSEL; ++i) pt[i] = __shfl_xor(t[i], 1);
    float L[5];
    #pragma unroll
    for (int i = 0; i < 5; ++i) L[i] = fmaxf(t[i], pt[KSEL - 1 - i]);
    float* Pg = P + ((size_t)(row0 + row) * NCHUNK + bn) * KSEL + half * 5;
    #pragma unroll
    for (int i = 0; i < 5; ++i) Pg[i] = L[i];
}

// ---- per-row merge of 256 chunk top-10s -> exact row top-10, sum into acc ---
__global__ void merge_topk_kernel(const float* __restrict__ P,
                                  float* __restrict__ fk_acc) {
    const int NC = NCHUNK * KSEL;   // 2560
    __shared__ float vals[NCHUNK * KSEL];
    __shared__ float wred[4];
    __shared__ float Mv_s;
    __shared__ int claim;
    int row = blockIdx.x;
    for (int i = threadIdx.x; i < NC; i += 256)
        vals[i] = P[(size_t)row * NC + i];
    __syncthreads();
    float sum10 = 0.0f;
    int lane = threadIdx.x & 63, w = threadIdx.x >> 6;
    for (int it = 0; it < KSEL; ++it) {
        float m = -FLT_MAX;
        for (int i = threadIdx.x; i < NC; i += 256) m = fmaxf(m, vals[i]);
        for (int o = 32; o > 0; o >>= 1) m = fmaxf(m, __shfl_down(m, o));
        if (lane == 0) wred[w] = m;
        __syncthreads();
        if (threadIdx.x == 0) {
            Mv_s = fmaxf(fmaxf(wred[0], wred[1]), fmaxf(wred[2], wred[3]));
            claim = 0;
        }
        __syncthreads();
        float Mv = Mv_s;
        for (int i = threadIdx.x; i < NC; i += 256) {
            if (vals[i] == Mv) {
                if (atomicCAS(&claim, 0, 1) == 0) vals[i] = -FLT_MAX;
                break;
            }
        }
        sum10 += Mv;
        __syncthreads();
    }
    if (threadIdx.x == 0) atomicAdd(fk_acc, sum10);
}

// ---- final scalar -----------------------------------------------------------
__global__ void finalize_kernel(const float* __restrict__ sc,
                                float* __restrict__ out) {
    if (threadIdx.x == 0) {
        float f = (sc[1] * 0.1f + sc[2] * 0.1f - 2.0f * sc[0]) * (1.0f / 4096.0f);
        out[0] = f;
    }
}

extern "C" void kernel_launch(void* const* d_in, const int* in_sizes, int n_in,
                              void* d_out, int out_size, void* d_ws, size_t ws_size,
                              hipStream_t stream) {
    const float* X_trans = (const float*)d_in[1];
    const float* Y_tgt   = (const float*)d_in[2];
    const float* Z_trans = (const float*)d_in[4];
    const float* Z_tgt   = (const float*)d_in[5];

    char* ws = (char*)d_ws;
    float* sc = (float*)ws;                                  // [0]=dot [1]=fk0 [2]=fk1
    unsigned short* A0 = (unsigned short*)(ws + 256);        // X_trans bf16 [4096,512]
    unsigned short* A1 = A0 + (size_t)B_ROWS * D_K;          // Y_tgt  bf16
    unsigned short* B0 = A1 + (size_t)B_ROWS * D_K;          // Z_tgt  bf16 [32768,512]
    unsigned short* B1 = B0 + (size_t)N_COLS * D_K;          // Z_trans bf16
    float* P = (float*)(B1 + (size_t)N_COLS * D_K);          // partials [4096][256][10]

    zero_scalars<<<1, 64, 0, stream>>>(sc);

    cvt_kernel<<<2048, 256, 0, stream>>>((const float4*)X_trans, (ushort4*)A0,
                                         B_ROWS * D_K / 4);
    cvt_kernel<<<2048, 256, 0, stream>>>((const float4*)Y_tgt, (ushort4*)A1,
                                         B_ROWS * D_K / 4);
    cvt_kernel<<<16384, 256, 0, stream>>>((const float4*)Z_tgt, (ushort4*)B0,
                                          N_COLS * D_K / 4);
    cvt_kernel<<<16384, 256, 0, stream>>>((const float4*)Z_trans, (ushort4*)B1,
                                          N_COLS * D_K / 4);

    dot_kernel<<<1024, 256, 0, stream>>>(X_trans, Y_tgt, sc + 0, B_ROWS * D_K);

    dim3 ggrid(NCHUNK, B_ROWS / BM);
    gemm_topk_kernel<<<ggrid, 256, 0, stream>>>(A0, B0, P);
    merge_topk_kernel<<<B_ROWS, 256, 0, stream>>>(P, sc + 1);
    gemm_topk_kernel<<<ggrid, 256, 0, stream>>>(A1, B1, P);
    merge_topk_kernel<<<B_ROWS, 256, 0, stream>>>(P, sc + 2);

    finalize_kernel<<<1, 64, 0, stream>>>(sc, (float*)d_out);
}

// Round 3
// 829.287 us; speedup vs baseline: 1.2972x; 1.0731x over previous
//
#include <hip/hip_runtime.h>
#include <hip/hip_bf16.h>
#include <float.h>
#include <cstdint>

// ---------------------------------------------------------------------------
// RCSLS: out = ( topk10sum(X_trans@Z_tgt^T)/10 + topk10sum(Y_tgt@Z_trans^T)/10
//               - 2*sum(X_trans*Y_tgt) ) / 4096
// B=4096, N=32768, d=512, k=10.  Inputs f32; GEMMs in bf16 MFMA.
// Top-k carried as sortable-u16 (monotone bf16 map) for packed 16-bit sorts.
// ---------------------------------------------------------------------------

#define B_ROWS 4096
#define N_COLS 32768
#define D_K    512
#define BM     128
#define BN     128
#define BKT    64
#define NCHUNK (N_COLS / BN)   // 256
#define KSEL   10
#define CSTRIDE 134            // u16 C-dump stride: dump AND scan conflict-free

typedef __bf16 bf16x8 __attribute__((ext_vector_type(8)));
typedef float  f32x4  __attribute__((ext_vector_type(4)));
typedef unsigned short u16x2 __attribute__((ext_vector_type(2)));

__device__ __forceinline__ unsigned short f2bf(float f) {
    unsigned int u = __float_as_uint(f);
    u += 0x7FFFu + ((u >> 16) & 1u);   // RNE
    return (unsigned short)(u >> 16);
}
// monotone map: f32 order == unsigned order of f2sort(f)
__device__ __forceinline__ unsigned short f2sort(float f) {
    unsigned int x = f2bf(f);
    return (unsigned short)(x ^ (0x8000u | ((x >> 15) * 0x7FFFu)));
}
__device__ __forceinline__ float sort2f(unsigned int y) {
    unsigned int x = (y & 0x8000u) ? (y ^ 0x8000u) : (~y & 0xFFFFu);
    return __uint_as_float(x << 16);
}

__device__ __forceinline__ void gload_lds16(const void* g, void* l) {
    __builtin_amdgcn_global_load_lds(
        (const __attribute__((address_space(1))) unsigned int*)(uintptr_t)g,
        (__attribute__((address_space(3))) unsigned int*)(uintptr_t)l,
        16, 0, 0);
}

// ---- zero the 3 scalar accumulators -----------------------------------------
__global__ void zero_scalars(float* sc) {
    if (threadIdx.x < 3) sc[threadIdx.x] = 0.0f;
}

// ---- fused f32->bf16 conversion (4 arrays) + dot(X,Y); grid.y selects ------
__global__ void prep_kernel(const float4* __restrict__ X,
                            const float4* __restrict__ Y,
                            const float4* __restrict__ Zt,
                            const float4* __restrict__ Ztr,
                            ushort4* __restrict__ A0, ushort4* __restrict__ A1,
                            ushort4* __restrict__ B0, ushort4* __restrict__ B1,
                            float* __restrict__ dotacc) {
    const int z = blockIdx.y;
    int i = blockIdx.x * 256 + threadIdx.x;
    const int stride = gridDim.x * 256;
    if (z == 0) {
        float s = 0.0f;
        for (; i < B_ROWS * D_K / 4; i += stride) {
            float4 x = X[i], y = Y[i];
            ushort4 u; u.x = f2bf(x.x); u.y = f2bf(x.y);
            u.z = f2bf(x.z); u.w = f2bf(x.w);
            A0[i] = u;
            s += x.x * y.x + x.y * y.y + x.z * y.z + x.w * y.w;
        }
        for (int o = 32; o > 0; o >>= 1) s += __shfl_down(s, o);
        __shared__ float wsum[4];
        int lane = threadIdx.x & 63, w = threadIdx.x >> 6;
        if (lane == 0) wsum[w] = s;
        __syncthreads();
        if (threadIdx.x == 0)
            atomicAdd(dotacc, wsum[0] + wsum[1] + wsum[2] + wsum[3]);
    } else {
        const float4* src = (z == 1) ? Y : (z == 2) ? Zt : Ztr;
        ushort4* dst = (z == 1) ? A1 : (z == 2) ? B0 : B1;
        int n4 = (z == 1) ? (B_ROWS * D_K / 4) : (N_COLS * D_K / 4);
        for (; i < n4; i += stride) {
            float4 f = src[i];
            ushort4 u; u.x = f2bf(f.x); u.y = f2bf(f.y);
            u.z = f2bf(f.z); u.w = f2bf(f.w);
            dst[i] = u;
        }
    }
}

// ---- bf16 GEMM (A[4096,512] @ Bm[32768,512]^T) + per-row per-chunk top-10 ---
// 1D grid 8192, XCD-swizzled: xcd = b&7 owns chunks [xcd*32, xcd*32+32),
// iterating 16-chunk groups over all row-blocks (B slice 2 MB stays in L2).
// Per (row,chunk): 2 threads write top-10 of their 64-col half as sortable u16
// -> P[row][chunk][half][10] u16 (candidate superset of row top-10).
__global__ __launch_bounds__(256, 4)
void gemm_topk_kernel(const unsigned short* __restrict__ A,
                      const unsigned short* __restrict__ Bm,
                      unsigned int* __restrict__ P32) {
    __shared__ __align__(128) unsigned short smem[BM * CSTRIDE]; // 34304 B
    unsigned short* Alds = smem;             // 16 segs * 512 shorts (16 KB)
    unsigned short* Blds = smem + 16 * 512;  // 16 KB

    const int tid  = threadIdx.x;
    const int lane = tid & 63;
    const int w    = tid >> 6;
    const int wm   = w >> 1;
    const int wn   = w & 1;
    const int quad = lane >> 4;
    const int mrow = lane & 15;

    // XCD swizzle
    const int b      = blockIdx.x;
    const int xcd    = b & 7;
    const int ii     = b >> 3;            // 0..1023
    const int cw     = ii & 15;
    const int rowblk = (ii >> 4) & 31;
    const int cg     = ii >> 9;           // 0..1
    const int bn     = xcd * 32 + cg * 16 + cw;
    const int row0   = rowblk * BM;
    const int col0   = bn * BN;

    // per-lane global staging offsets (segment s = w*4+c):
    //   row-in-tile = (s>>1)*16 + (lane&15); col = (s&1)*32 + (lane>>4)*8
    const unsigned short* gA[4];
    const unsigned short* gB[4];
    #pragma unroll
    for (int c = 0; c < 4; ++c) {
        int s  = w * 4 + c;
        int r  = (s >> 1) * 16 + mrow;
        int kc = (s & 1) * 32 + quad * 8;
        gA[c] = A  + (size_t)(row0 + r) * D_K + kc;
        gB[c] = Bm + (size_t)(col0 + r) * D_K + kc;
    }

    f32x4 acc[4][4];
    #pragma unroll
    for (int mi = 0; mi < 4; ++mi)
        #pragma unroll
        for (int ni = 0; ni < 4; ++ni)
            acc[mi][ni] = (f32x4){0.f, 0.f, 0.f, 0.f};

    for (int kt = 0; kt < D_K; kt += BKT) {
        #pragma unroll
        for (int c = 0; c < 4; ++c) {
            int s = w * 4 + c;
            gload_lds16(gA[c] + kt, Alds + s * 512);
            gload_lds16(gB[c] + kt, Blds + s * 512);
        }
        __syncthreads();
        #pragma unroll
        for (int kk32 = 0; kk32 < 2; ++kk32) {
            bf16x8 af[4], bfr[4];
            #pragma unroll
            for (int mi = 0; mi < 4; ++mi)
                af[mi] = *(const bf16x8*)(Alds + ((wm * 4 + mi) * 2 + kk32) * 512 + lane * 8);
            #pragma unroll
            for (int ni = 0; ni < 4; ++ni)
                bfr[ni] = *(const bf16x8*)(Blds + ((wn * 4 + ni) * 2 + kk32) * 512 + lane * 8);
            #pragma unroll
            for (int mi = 0; mi < 4; ++mi)
                #pragma unroll
                for (int ni = 0; ni < 4; ++ni)
                    acc[mi][ni] = __builtin_amdgcn_mfma_f32_16x16x32_bf16(
                        af[mi], bfr[ni], acc[mi][ni], 0, 0, 0);
        }
        __syncthreads();
    }

    // ---- dump C as sortable u16, stride 134 (conflict-free) ----
    unsigned short* Cs = smem;
    #pragma unroll
    for (int mi = 0; mi < 4; ++mi) {
        int r = wm * 64 + mi * 16 + quad * 4;
        #pragma unroll
        for (int ni = 0; ni < 4; ++ni) {
            int cc = wn * 64 + ni * 16 + mrow;
            #pragma unroll
            for (int reg = 0; reg < 4; ++reg)
                Cs[(r + reg) * CSTRIDE + cc] = f2sort(acc[mi][ni][reg]);
        }
    }
    __syncthreads();

    // ---- per-half-row packed top-10: row = w*32+(lane>>1), half = lane&1 ----
    const int row  = w * 32 + (lane >> 1);
    const int half = lane & 1;
    const u16x2* rp = (const u16x2*)(Cs + row * CSTRIDE + half * 64);
    u16x2 t[KSEL];
    #pragma unroll
    for (int i = 0; i < KSEL; ++i) t[i] = (u16x2){0, 0};
    #pragma unroll 8
    for (int j = 0; j < 32; ++j) {
        u16x2 v = rp[j];                       // (even col, odd col)
        #pragma unroll
        for (int i = 0; i < KSEL; ++i) {
            u16x2 hi = __builtin_elementwise_max(t[i], v);
            v = __builtin_elementwise_min(t[i], v);
            t[i] = hi;
        }
    }
    // merge the two sorted streams -> top-10 multiset of this 64-col half
    unsigned int m[KSEL];
    #pragma unroll
    for (int i = 0; i < KSEL; ++i)
        m[i] = max((unsigned int)t[i].x, (unsigned int)t[KSEL - 1 - i].y);
    unsigned int* Pg = P32 + ((size_t)(row0 + row) * NCHUNK + bn) * KSEL + half * 5;
    #pragma unroll
    for (int i = 0; i < 5; ++i)
        Pg[i] = m[2 * i] | (m[2 * i + 1] << 16);
}

// ---- per-row exact top-10 over 5120 u16 candidates; one wave per row --------
__global__ __launch_bounds__(256, 4)
void merge_topk_kernel(const unsigned int* __restrict__ P32,
                       float* __restrict__ fk_acc) {
    const int lane = threadIdx.x & 63;
    const int w    = threadIdx.x >> 6;
    const int row  = blockIdx.x * 4 + w;
    const unsigned int* Rp = P32 + (size_t)row * (NCHUNK * KSEL); // 2560 u32

    u16x2 t[KSEL];
    #pragma unroll
    for (int i = 0; i < KSEL; ++i) t[i] = (u16x2){0, 0};
    #pragma unroll 4
    for (int it = 0; it < 40; ++it) {
        unsigned int raw = Rp[lane + 64 * it];
        u16x2 v = *(u16x2*)&raw;
        #pragma unroll
        for (int i = 0; i < KSEL; ++i) {
            u16x2 hi = __builtin_elementwise_max(t[i], v);
            v = __builtin_elementwise_min(t[i], v);
            t[i] = hi;
        }
    }
    // per-lane top-10 multiset, packed with (lane,slot) for unique extraction
    unsigned int wreg[KSEL];
    #pragma unroll
    for (int i = 0; i < KSEL; ++i) {
        unsigned int mv = max((unsigned int)t[i].x,
                              (unsigned int)t[KSEL - 1 - i].y);
        wreg[i] = (mv << 16) | ((unsigned int)lane << 4) | (unsigned int)i;
    }
    float sum10 = 0.0f;
    #pragma unroll
    for (int iter = 0; iter < KSEL; ++iter) {
        unsigned int mx = wreg[0];
        #pragma unroll
        for (int s = 1; s < KSEL; ++s) mx = max(mx, wreg[s]);
        #pragma unroll
        for (int o = 32; o > 0; o >>= 1)
            mx = max(mx, (unsigned int)__shfl_xor((int)mx, o));
        sum10 += sort2f(mx >> 16);
        #pragma unroll
        for (int s = 0; s < KSEL; ++s)
            if (wreg[s] == mx) wreg[s] = 0u;
    }
    if (lane == 0) atomicAdd(fk_acc, sum10);
}

// ---- final scalar -----------------------------------------------------------
__global__ void finalize_kernel(const float* __restrict__ sc,
                                float* __restrict__ out) {
    if (threadIdx.x == 0) {
        float f = (sc[1] * 0.1f + sc[2] * 0.1f - 2.0f * sc[0]) * (1.0f / 4096.0f);
        out[0] = f;
    }
}

extern "C" void kernel_launch(void* const* d_in, const int* in_sizes, int n_in,
                              void* d_out, int out_size, void* d_ws, size_t ws_size,
                              hipStream_t stream) {
    const float* X_trans = (const float*)d_in[1];
    const float* Y_tgt   = (const float*)d_in[2];
    const float* Z_trans = (const float*)d_in[4];
    const float* Z_tgt   = (const float*)d_in[5];

    char* ws = (char*)d_ws;
    float* sc = (float*)ws;                                  // [0]=dot [1]=fk0 [2]=fk1
    unsigned short* A0 = (unsigned short*)(ws + 256);        // X_trans bf16 [4096,512]
    unsigned short* A1 = A0 + (size_t)B_ROWS * D_K;          // Y_tgt  bf16
    unsigned short* B0 = A1 + (size_t)B_ROWS * D_K;          // Z_tgt  bf16 [32768,512]
    unsigned short* B1 = B0 + (size_t)N_COLS * D_K;          // Z_trans bf16
    unsigned int* P = (unsigned int*)(B1 + (size_t)N_COLS * D_K); // [4096][256][10] u32

    zero_scalars<<<1, 64, 0, stream>>>(sc);

    dim3 pgrid(2048, 4);
    prep_kernel<<<pgrid, 256, 0, stream>>>(
        (const float4*)X_trans, (const float4*)Y_tgt,
        (const float4*)Z_tgt, (const float4*)Z_trans,
        (ushort4*)A0, (ushort4*)A1, (ushort4*)B0, (ushort4*)B1, sc + 0);

    gemm_topk_kernel<<<8192, 256, 0, stream>>>(A0, B0, P);
    merge_topk_kernel<<<B_ROWS / 4, 256, 0, stream>>>(P, sc + 1);
    gemm_topk_kernel<<<8192, 256, 0, stream>>>(A1, B1, P);
    merge_topk_kernel<<<B_ROWS / 4, 256, 0, stream>>>(P, sc + 2);

    finalize_kernel<<<1, 64, 0, stream>>>(sc, (float*)d_out);
}